// Round 18
// baseline (159.832 us; speedup 1.0000x reference)
//
#include <hip/hip_runtime.h>
#include <hip/hip_bf16.h>

// Problem constants
#define B_   16
#define C_   64
#define G_   256
#define P_   4096
#define W_   1024
#define H_   256
#define WQ_  256
#define M_   (B_ * P_)   // 65536 flattened (b,p) rows

typedef __attribute__((ext_vector_type(8))) _Float16 f16x8;  // MFMA A/B frag
typedef __attribute__((ext_vector_type(4))) float    f32x4;  // MFMA C/D frag

__device__ __forceinline__ float h2f(ushort u) {
    union { ushort u; _Float16 h; } cv; cv.u = u;
    return (float)cv.h;
}

// async global->LDS, 16B per lane (dest = wave-uniform base + lane*16)
#define GLOAD16(gsrc, ldst)                                                  \
    __builtin_amdgcn_global_load_lds(                                        \
        (const __attribute__((address_space(1))) unsigned int*)(gsrc),       \
        (__attribute__((address_space(3))) unsigned int*)(ldst), 16, 0, 0)

// Inverse of the 64B-row XOR swizzle  p = l ^ (((l>>6)&7)<<4)
__device__ __forceinline__ int inv_swz64(int o) {
    const int b8 = (o >> 8) & 1, b7 = (o >> 7) & 1, b6 = (o >> 6) & 1;
    const int b5 = (o >> 5) & 1, b4 = (o >> 4) & 1;
    const int l6 = b6 ^ b8, l5 = b5 ^ b7, l4 = b4 ^ l6;
    return (o & ~0x70) | (l6 << 6) | (l5 << 5) | (l4 << 4);
}

// ---------------------------------------------------------------------------
// Setup kernel: convT16(Ww), convT16(W1w), prep — one launch, 96 blocks.
// ---------------------------------------------------------------------------
__device__ __forceinline__ void convT_dev(
    const float* __restrict__ src, ushort* __restrict__ dst,
    int K, int N, int blk, float* tile /* 64*65 floats */)
{
    const int nb = N >> 6;
    const int k0 = (blk / nb) * 64;
    const int n0 = (blk % nb) * 64;
    const int t = threadIdx.x;
    #pragma unroll
    for (int i = 0; i < 16; ++i) {
        int e = i * 256 + t;
        int kr = e >> 6, nc = e & 63;
        tile[nc * 65 + kr] = src[(size_t)(k0 + kr) * N + n0 + nc];
    }
    __syncthreads();
    #pragma unroll
    for (int i = 0; i < 16; ++i) {
        int e = i * 256 + t;
        int nc = e >> 6, kr = e & 63;
        union { _Float16 h; ushort u; } cv;
        cv.h = (_Float16)tile[nc * 65 + kr];
        dst[(size_t)(n0 + nc) * K + k0 + kr] = cv.u;
    }
}

__global__ __launch_bounds__(256) void setup_kernel(
    const float* __restrict__ Ww,  ushort* __restrict__ WwT,
    const float* __restrict__ W1w, ushort* __restrict__ W1T,
    const float* __restrict__ cx, const float* __restrict__ gx,
    const float* __restrict__ Wc, const float* __restrict__ bc,
    const float* __restrict__ Wg, const float* __restrict__ bg,
    const float* __restrict__ W1, const float* __restrict__ b1,
    float* __restrict__ base_out)
{
    __shared__ float smem[64 * 65];
    const int blk = blockIdx.x;
    if (blk < 64) {
        convT_dev(Ww, WwT, W_, WQ_, blk, smem);
        return;
    }
    if (blk < 80) {
        convT_dev(W1w, W1T, H_, H_, blk - 64, smem);
        return;
    }
    const int b = blk - 80;
    const int t = threadIdx.x;
    float* cxl = smem;
    float* gxl = smem + 64;
    float* cl  = smem + 320;
    float* gl  = smem + 384;

    if (t < C_) cxl[t] = cx[b * C_ + t];
    gxl[t] = gx[b * G_ + t];
    __syncthreads();

    if (t < C_) {
        float acc = bc[t];
        #pragma unroll 4
        for (int i = 0; i < C_; ++i) acc += cxl[i] * Wc[i * C_ + t];
        cl[t] = acc;
    }
    {
        float acc = bg[t];
        #pragma unroll 4
        for (int i = 0; i < G_; ++i) acc += gxl[i] * Wg[i * G_ + t];
        gl[t] = acc;
    }
    __syncthreads();

    float acc = b1[t];
    #pragma unroll 4
    for (int i = 0; i < C_; ++i) acc += cl[i] * W1[i * H_ + t];
    #pragma unroll 4
    for (int i = 0; i < G_; ++i) acc += gl[i] * W1[(C_ + i) * H_ + t];
    base_out[b * H_ + t] = acc;
}

// ---------------------------------------------------------------------------
// Kernel 2: w GEMM — counted-vmcnt pipeline (T3+T4, R17-proven) + T5 setprio
// around the MFMA cluster (gated on exactly this schedule class — m218b).
// BM=128, BN=256(all), BK=32, dbuf (64 KB LDS -> 2 blocks/CU), 512 thr.
// grid = M/128 = 512
// ---------------------------------------------------------------------------
__global__ __launch_bounds__(512, 2) void gemm_w_mfma(
    const float* __restrict__ A,      // wx  M x 1024 fp32
    const ushort* __restrict__ BT,    // WwT fp16 [256][1024]
    const float* __restrict__ bw,
    ushort* __restrict__ Cout)        // w  M x 256 fp16
{
    __shared__ __align__(16) char smem[65536];
    // A bufs @0,16384: [128][32] f32, 128B rows.  B bufs @32768,49152:
    // [256][32] f16, 64B rows.

    const int t = threadIdx.x;
    const int row0 = blockIdx.x * 128;
    const int lane = t & 63, wave = t >> 6;
    const int wm = wave >> 2, wn = wave & 3;
    const int l15 = lane & 15, lq = lane >> 4;

    // A staging: linear dest (128B rows), in-row inverse swizzle
    const int oA0 = t * 16, oA1 = t * 16 + 8192;
    const int rA0 = oA0 >> 7, rA1 = oA1 >> 7;
    const float* srcA0 = A + (size_t)(row0 + rA0) * W_
                           + (((oA0 & 127) ^ ((rA0 & 7) << 4)) >> 2);
    const float* srcA1 = A + (size_t)(row0 + rA1) * W_
                           + (((oA1 & 127) ^ ((rA1 & 7) << 4)) >> 2);
    // B staging: linear dest (64B rows), full-address inv_swz64 bijection
    const int oB0 = t * 16, oB1 = t * 16 + 8192;
    const int lB0 = inv_swz64(oB0), lB1 = inv_swz64(oB1);
    const ushort* srcB0 = BT + (size_t)(lB0 >> 6) * W_ + ((lB0 & 63) >> 1);
    const ushort* srcB1 = BT + (size_t)(lB1 >> 6) * W_ + ((lB1 & 63) >> 1);

#define STAGE_W(BUF, K0)                                                     \
    {                                                                        \
        char* ab = smem + (BUF) * 16384;                                     \
        char* bb = smem + 32768 + (BUF) * 16384;                             \
        GLOAD16(srcA0 + (K0), ab + oA0);                                     \
        GLOAD16(srcA1 + (K0), ab + oA1);                                     \
        GLOAD16(srcB0 + (K0), bb + oB0);                                     \
        GLOAD16(srcB1 + (K0), bb + oB1);                                     \
    }

    f32x4 acc[4][4];
    #pragma unroll
    for (int m = 0; m < 4; ++m)
        #pragma unroll
        for (int n = 0; n < 4; ++n) acc[m][n] = (f32x4){0.f, 0.f, 0.f, 0.f};

    // prologue: tiles 0 and 1 in flight (8 outstanding/thread)
    STAGE_W(0, 0)
    STAGE_W(1, 32)

    #pragma unroll 1
    for (int kt = 0; kt < 32; ++kt) {
        const int cur = kt & 1;
        // tile kt ready when only the newest 4 loads remain outstanding
        if (kt < 31) asm volatile("s_waitcnt vmcnt(4)" ::: "memory");
        else         asm volatile("s_waitcnt vmcnt(0)" ::: "memory");
        __builtin_amdgcn_sched_barrier(0);
        __builtin_amdgcn_s_barrier();     // all waves: buf[cur] complete

        const char* Af = smem + cur * 16384;
        const char* Bh = smem + 32768 + cur * 16384;
        f16x8 af[4], bf[4];
        #pragma unroll
        for (int m = 0; m < 4; ++m) {
            const int r = wm * 64 + m * 16 + l15;
            const int base = r * 128 + lq * 32;
            const int swz  = (r & 7) << 4;
            const f32x4 a0 = *(const f32x4*)(Af + (base ^ swz));
            const f32x4 a1 = *(const f32x4*)(Af + ((base + 16) ^ swz));
            f16x8 h;
            h[0] = (_Float16)a0[0]; h[1] = (_Float16)a0[1];
            h[2] = (_Float16)a0[2]; h[3] = (_Float16)a0[3];
            h[4] = (_Float16)a1[0]; h[5] = (_Float16)a1[1];
            h[6] = (_Float16)a1[2]; h[7] = (_Float16)a1[3];
            af[m] = h;
        }
        #pragma unroll
        for (int n = 0; n < 4; ++n) {
            const int c = wn * 64 + n * 16 + l15;
            bf[n] = *(const f16x8*)(Bh + ((c * 64 + lq * 16) ^ ((c & 7) << 4)));
        }
        __builtin_amdgcn_s_setprio(1);    // T5: favor MFMA-issuing wave
        #pragma unroll
        for (int m = 0; m < 4; ++m)
            #pragma unroll
            for (int n = 0; n < 4; ++n)
                acc[m][n] = __builtin_amdgcn_mfma_f32_16x16x32_f16(
                    af[m], bf[n], acc[m][n], 0, 0, 0);
        __builtin_amdgcn_s_setprio(0);

        __builtin_amdgcn_sched_barrier(0);
        __builtin_amdgcn_s_barrier();     // all waves done reading buf[cur]
        if (kt + 2 < 32) STAGE_W(cur, (kt + 2) * 32)
    }
#undef STAGE_W

    // epilogue: w16 -> global
    float bwv[4];
    #pragma unroll
    for (int n = 0; n < 4; ++n) bwv[n] = bw[wn * 64 + n * 16 + l15];
    #pragma unroll
    for (int m = 0; m < 4; ++m)
        #pragma unroll
        for (int reg = 0; reg < 4; ++reg) {
            const size_t r = (size_t)row0 + wm * 64 + m * 16 + lq * 4 + reg;
            #pragma unroll
            for (int n = 0; n < 4; ++n) {
                union { _Float16 h; ushort u; } cv;
                cv.h = (_Float16)(acc[m][n][reg] + bwv[n]);
                Cout[r * WQ_ + wn * 64 + n * 16 + l15] = cv.u;
            }
        }
}

// ---------------------------------------------------------------------------
// Kernel 3: scores — counted-vmcnt pipeline port (same transformation as
// gemm_w; L=3 loads/tile -> head wait vmcnt(3)). dbuf 48KB + red 2KB.
// BM=128, BN=256(all), BK=32, 8 K-tiles, 512 thr. grid = M/128 = 512
// ---------------------------------------------------------------------------
__global__ __launch_bounds__(512, 2) void gemm_scores_mfma(
    const ushort* __restrict__ A16,   // w M x 256 fp16
    const ushort* __restrict__ BT,    // W1wT fp16 [256][256]
    const float* __restrict__ base_,  // B_ x 256
    const float* __restrict__ W2,     // 256
    const float* __restrict__ b2,     // 1
    float* __restrict__ scores)       // M
{
    __shared__ __align__(16) char smem[49152];
    // A bufs @0,8192: [128][32] f16, 64B rows. B bufs @16384,32768: [256][32] f16
    __shared__ float red[4][128];
    const int t = threadIdx.x;
    const int row0 = blockIdx.x * 128;
    const int b = blockIdx.x >> 5;
    const int lane = t & 63, wave = t >> 6;
    const int wm = wave >> 2, wn = wave & 3;
    const int l15 = lane & 15, lq = lane >> 4;

    // A staging: 1 granule/thread (threads 0..511 cover 8KB)
    const int oA = t * 16;
    const int lA = inv_swz64(oA);
    const ushort* srcA = A16 + (size_t)(row0 + (lA >> 6)) * H_ + ((lA & 63) >> 1);
    // B staging: 2 granules/thread
    const int oB0 = t * 16, oB1 = t * 16 + 8192;
    const int lB0 = inv_swz64(oB0), lB1 = inv_swz64(oB1);
    const ushort* srcB0 = BT + (size_t)(lB0 >> 6) * H_ + ((lB0 & 63) >> 1);
    const ushort* srcB1 = BT + (size_t)(lB1 >> 6) * H_ + ((lB1 & 63) >> 1);

#define STAGE_S(BUF, K0)                                                     \
    {                                                                        \
        char* ab = smem + (BUF) * 8192;                                      \
        char* bb = smem + 16384 + (BUF) * 16384;                             \
        GLOAD16(srcA + (K0), ab + oA);                                       \
        GLOAD16(srcB0 + (K0), bb + oB0);                                     \
        GLOAD16(srcB1 + (K0), bb + oB1);                                     \
    }

    f32x4 acc[4][4];
    #pragma unroll
    for (int m = 0; m < 4; ++m)
        #pragma unroll
        for (int n = 0; n < 4; ++n) acc[m][n] = (f32x4){0.f, 0.f, 0.f, 0.f};

    STAGE_S(0, 0)
    STAGE_S(1, 32)

    #pragma unroll 1
    for (int kt = 0; kt < 8; ++kt) {
        const int cur = kt & 1;
        if (kt < 7) asm volatile("s_waitcnt vmcnt(3)" ::: "memory");
        else        asm volatile("s_waitcnt vmcnt(0)" ::: "memory");
        __builtin_amdgcn_sched_barrier(0);
        __builtin_amdgcn_s_barrier();

        const char* Ah = smem + cur * 8192;
        const char* Bh = smem + 16384 + cur * 16384;
        f16x8 af[4], bf[4];
        #pragma unroll
        for (int m = 0; m < 4; ++m) {
            const int r = wm * 64 + m * 16 + l15;
            af[m] = *(const f16x8*)(Ah + ((r * 64 + lq * 16) ^ ((r & 7) << 4)));
        }
        #pragma unroll
        for (int n = 0; n < 4; ++n) {
            const int c = wn * 64 + n * 16 + l15;
            bf[n] = *(const f16x8*)(Bh + ((c * 64 + lq * 16) ^ ((c & 7) << 4)));
        }
        __builtin_amdgcn_s_setprio(1);
        #pragma unroll
        for (int m = 0; m < 4; ++m)
            #pragma unroll
            for (int n = 0; n < 4; ++n)
                acc[m][n] = __builtin_amdgcn_mfma_f32_16x16x32_f16(
                    af[m], bf[n], acc[m][n], 0, 0, 0);
        __builtin_amdgcn_s_setprio(0);

        __builtin_amdgcn_sched_barrier(0);
        __builtin_amdgcn_s_barrier();
        if (kt + 2 < 8) STAGE_S(cur, (kt + 2) * 32)
    }
#undef STAGE_S

    float basev[4], w2v[4];
    #pragma unroll
    for (int n = 0; n < 4; ++n) {
        const int col = wn * 64 + n * 16 + l15;
        basev[n] = base_[b * H_ + col];
        w2v[n] = W2[col];
    }
    #pragma unroll
    for (int m = 0; m < 4; ++m)
        #pragma unroll
        for (int reg = 0; reg < 4; ++reg) {
            float s = 0.f;
            #pragma unroll
            for (int n = 0; n < 4; ++n) {
                float h = acc[m][n][reg] + basev[n];
                h = fmaxf(h, 0.f);
                s += h * w2v[n];
            }
            s += __shfl_xor(s, 1, 64);
            s += __shfl_xor(s, 2, 64);
            s += __shfl_xor(s, 4, 64);
            s += __shfl_xor(s, 8, 64);
            if (l15 == 0) red[wn][wm * 64 + m * 16 + lq * 4 + reg] = s;
        }
    __syncthreads();
    if (t < 128) {
        scores[row0 + t] = red[0][t] + red[1][t] + red[2][t] + red[3][t] + b2[0];
    }
}

// ---------------------------------------------------------------------------
// Kernel 4: weighted partial sums; m computed locally (identical reduction
// code to finalize -> bitwise-identical m). grid = B_*32, 256 threads.
// ---------------------------------------------------------------------------
__global__ __launch_bounds__(256) void weighted_partial_kernel(
    const ushort* __restrict__ wmat16, const float* __restrict__ scores,
    float* __restrict__ part)
{
    const int blk = blockIdx.x;
    const int b   = blk >> 5;
    const int sl  = blk & 31;
    const int t   = threadIdx.x;
    const int rg  = t >> 5;
    const int q8  = (t & 31) * 8;
    __shared__ float red[8][WQ_];
    __shared__ float mred[4];

    float mv = -1e30f;
    for (int p = t; p < P_; p += 256) mv = fmaxf(mv, scores[b * P_ + p]);
    #pragma unroll
    for (int d = 1; d < 64; d <<= 1) mv = fmaxf(mv, __shfl_xor(mv, d, 64));
    if ((t & 63) == 0) mred[t >> 6] = mv;
    __syncthreads();
    const float m = fmaxf(fmaxf(mred[0], mred[1]), fmaxf(mred[2], mred[3]));

    float acc[8];
    #pragma unroll
    for (int j = 0; j < 8; ++j) acc[j] = 0.f;

    const int p0 = sl * 128 + rg * 16;
    for (int p = p0; p < p0 + 16; ++p) {
        const float e = expf(scores[b * P_ + p] - m);
        const uint4 raw = *(const uint4*)(wmat16 + ((size_t)b * P_ + p) * WQ_ + q8);
        const ushort* u = (const ushort*)&raw;
        #pragma unroll
        for (int j = 0; j < 8; ++j) acc[j] += e * h2f(u[j]);
    }
    #pragma unroll
    for (int j = 0; j < 8; ++j) red[rg][q8 + j] = acc[j];
    __syncthreads();
    float s = 0.f;
    #pragma unroll
    for (int g = 0; g < 8; ++g) s += red[g][t];
    part[(size_t)(b * 32 + sl) * WQ_ + t] = s;
}

// ---------------------------------------------------------------------------
// Kernel 5: finalize — recompute m (same code) and z, out = sum(part)/z.
// ---------------------------------------------------------------------------
__global__ __launch_bounds__(256) void finalize_kernel(
    const float* __restrict__ part, const float* __restrict__ scores,
    float* __restrict__ out)
{
    const int b = blockIdx.x;
    const int t = threadIdx.x;
    __shared__ float mred[4];
    __shared__ float zred[4];

    float mv = -1e30f;
    for (int p = t; p < P_; p += 256) mv = fmaxf(mv, scores[b * P_ + p]);
    #pragma unroll
    for (int d = 1; d < 64; d <<= 1) mv = fmaxf(mv, __shfl_xor(mv, d, 64));
    if ((t & 63) == 0) mred[t >> 6] = mv;
    __syncthreads();
    const float m = fmaxf(fmaxf(mred[0], mred[1]), fmaxf(mred[2], mred[3]));

    float zv = 0.f;
    for (int p = t; p < P_; p += 256) zv += expf(scores[b * P_ + p] - m);
    #pragma unroll
    for (int d = 1; d < 64; d <<= 1) zv += __shfl_xor(zv, d, 64);
    if ((t & 63) == 0) zred[t >> 6] = zv;
    __syncthreads();
    const float z = zred[0] + zred[1] + zred[2] + zred[3];

    float acc = 0.f;
    #pragma unroll
    for (int sl = 0; sl < 32; ++sl) acc += part[(size_t)(b * 32 + sl) * WQ_ + t];
    out[b * WQ_ + t] = acc / z;
}

// ---------------------------------------------------------------------------
extern "C" void kernel_launch(void* const* d_in, const int* in_sizes, int n_in,
                              void* d_out, int out_size, void* d_ws, size_t ws_size,
                              hipStream_t stream) {
    const float* cx = (const float*)d_in[0];
    const float* gx = (const float*)d_in[1];
    const float* wx = (const float*)d_in[2];
    const float* Wc = (const float*)d_in[3];
    const float* bc = (const float*)d_in[4];
    const float* Wg = (const float*)d_in[5];
    const float* bg = (const float*)d_in[6];
    const float* Ww = (const float*)d_in[7];
    const float* bw = (const float*)d_in[8];
    const float* W1 = (const float*)d_in[9];
    const float* b1 = (const float*)d_in[10];
    const float* W2 = (const float*)d_in[11];
    const float* b2 = (const float*)d_in[12];
    float* out = (float*)d_out;

    // workspace layout
    float* ws        = (float*)d_ws;
    ushort* ws_w16   = (ushort*)ws;                      // M_*WQ_ fp16 (32 MB)
    float* ws_scores = ws + (size_t)M_ * WQ_ / 2;        // M_
    float* ws_base   = ws_scores + M_;                   // B_*H_
    float* ws_part   = ws_base + B_ * H_;                // B_*32*WQ_
    ushort* WwT16    = (ushort*)(ws_part + B_ * 32 * WQ_);   // W_*WQ_ fp16
    ushort* W1T16    = WwT16 + (size_t)W_ * WQ_;             // H_*H_ fp16

    setup_kernel<<<96, 256, 0, stream>>>(
        Ww, WwT16, W1 + (size_t)(C_ + G_) * H_, W1T16,
        cx, gx, Wc, bc, Wg, bg, W1, b1, ws_base);

    gemm_w_mfma<<<M_ / 128, 512, 0, stream>>>(wx, WwT16, bw, ws_w16);

    gemm_scores_mfma<<<M_ / 128, 512, 0, stream>>>(
        ws_w16, W1T16, ws_base, W2, b2, ws_scores);

    weighted_partial_kernel<<<B_ * 32, 256, 0, stream>>>(ws_w16, ws_scores, ws_part);

    finalize_kernel<<<B_, 256, 0, stream>>>(ws_part, ws_scores, out);
}

// Round 22
// 152.870 us; speedup vs baseline: 1.0455x; 1.0455x over previous
//
#include <hip/hip_runtime.h>
#include <hip/hip_bf16.h>

// Problem constants
#define B_   16
#define C_   64
#define G_   256
#define P_   4096
#define W_   1024
#define H_   256
#define WQ_  256
#define M_   (B_ * P_)   // 65536 flattened (b,p) rows

typedef __attribute__((ext_vector_type(8))) _Float16 f16x8;  // MFMA A/B frag
typedef __attribute__((ext_vector_type(4))) float    f32x4;  // MFMA C/D frag

__device__ __forceinline__ float h2f(ushort u) {
    union { ushort u; _Float16 h; } cv; cv.u = u;
    return (float)cv.h;
}

// async global->LDS, 16B per lane (dest = wave-uniform base + lane*16)
#define GLOAD16(gsrc, ldst)                                                  \
    __builtin_amdgcn_global_load_lds(                                        \
        (const __attribute__((address_space(1))) unsigned int*)(gsrc),       \
        (__attribute__((address_space(3))) unsigned int*)(ldst), 16, 0, 0)

// Inverse of the 64B-row XOR swizzle  p = l ^ (((l>>6)&7)<<4)
__device__ __forceinline__ int inv_swz64(int o) {
    const int b8 = (o >> 8) & 1, b7 = (o >> 7) & 1, b6 = (o >> 6) & 1;
    const int b5 = (o >> 5) & 1, b4 = (o >> 4) & 1;
    const int l6 = b6 ^ b8, l5 = b5 ^ b7, l4 = b4 ^ l6;
    return (o & ~0x70) | (l6 << 6) | (l5 << 5) | (l4 << 4);
}

// ---------------------------------------------------------------------------
// Setup kernel: convT16(Ww), convT16(W1w), prep — one launch, 96 blocks.
// ---------------------------------------------------------------------------
__device__ __forceinline__ void convT_dev(
    const float* __restrict__ src, ushort* __restrict__ dst,
    int K, int N, int blk, float* tile /* 64*65 floats */)
{
    const int nb = N >> 6;
    const int k0 = (blk / nb) * 64;
    const int n0 = (blk % nb) * 64;
    const int t = threadIdx.x;
    #pragma unroll
    for (int i = 0; i < 16; ++i) {
        int e = i * 256 + t;
        int kr = e >> 6, nc = e & 63;
        tile[nc * 65 + kr] = src[(size_t)(k0 + kr) * N + n0 + nc];
    }
    __syncthreads();
    #pragma unroll
    for (int i = 0; i < 16; ++i) {
        int e = i * 256 + t;
        int nc = e >> 6, kr = e & 63;
        union { _Float16 h; ushort u; } cv;
        cv.h = (_Float16)tile[nc * 65 + kr];
        dst[(size_t)(n0 + nc) * K + k0 + kr] = cv.u;
    }
}

__global__ __launch_bounds__(256) void setup_kernel(
    const float* __restrict__ Ww,  ushort* __restrict__ WwT,
    const float* __restrict__ W1w, ushort* __restrict__ W1T,
    const float* __restrict__ cx, const float* __restrict__ gx,
    const float* __restrict__ Wc, const float* __restrict__ bc,
    const float* __restrict__ Wg, const float* __restrict__ bg,
    const float* __restrict__ W1, const float* __restrict__ b1,
    float* __restrict__ base_out)
{
    __shared__ float smem[64 * 65];
    const int blk = blockIdx.x;
    if (blk < 64) {
        convT_dev(Ww, WwT, W_, WQ_, blk, smem);
        return;
    }
    if (blk < 80) {
        convT_dev(W1w, W1T, H_, H_, blk - 64, smem);
        return;
    }
    const int b = blk - 80;
    const int t = threadIdx.x;
    float* cxl = smem;
    float* gxl = smem + 64;
    float* cl  = smem + 320;
    float* gl  = smem + 384;

    if (t < C_) cxl[t] = cx[b * C_ + t];
    gxl[t] = gx[b * G_ + t];
    __syncthreads();

    if (t < C_) {
        float acc = bc[t];
        #pragma unroll 4
        for (int i = 0; i < C_; ++i) acc += cxl[i] * Wc[i * C_ + t];
        cl[t] = acc;
    }
    {
        float acc = bg[t];
        #pragma unroll 4
        for (int i = 0; i < G_; ++i) acc += gxl[i] * Wg[i * G_ + t];
        gl[t] = acc;
    }
    __syncthreads();

    float acc = b1[t];
    #pragma unroll 4
    for (int i = 0; i < C_; ++i) acc += cl[i] * W1[i * H_ + t];
    #pragma unroll 4
    for (int i = 0; i < G_; ++i) acc += gl[i] * W1[(C_ + i) * H_ + t];
    base_out[b * H_ + t] = acc;
}

// ---------------------------------------------------------------------------
// Kernel 2: w GEMM — counted-vmcnt pipeline (T3+T4, R17-proven; setprio
// REMOVED — isolating R18's null-to-negative bundle).
// BM=128, BN=256(all), BK=32, dbuf (64 KB LDS -> 2 blocks/CU), 512 thr.
// grid = M/128 = 512
// ---------------------------------------------------------------------------
__global__ __launch_bounds__(512, 2) void gemm_w_mfma(
    const float* __restrict__ A,      // wx  M x 1024 fp32
    const ushort* __restrict__ BT,    // WwT fp16 [256][1024]
    const float* __restrict__ bw,
    ushort* __restrict__ Cout)        // w  M x 256 fp16
{
    __shared__ __align__(16) char smem[65536];
    // A bufs @0,16384: [128][32] f32, 128B rows.  B bufs @32768,49152:
    // [256][32] f16, 64B rows.

    const int t = threadIdx.x;
    const int row0 = blockIdx.x * 128;
    const int lane = t & 63, wave = t >> 6;
    const int wm = wave >> 2, wn = wave & 3;
    const int l15 = lane & 15, lq = lane >> 4;

    // A staging: linear dest (128B rows), in-row inverse swizzle
    const int oA0 = t * 16, oA1 = t * 16 + 8192;
    const int rA0 = oA0 >> 7, rA1 = oA1 >> 7;
    const float* srcA0 = A + (size_t)(row0 + rA0) * W_
                           + (((oA0 & 127) ^ ((rA0 & 7) << 4)) >> 2);
    const float* srcA1 = A + (size_t)(row0 + rA1) * W_
                           + (((oA1 & 127) ^ ((rA1 & 7) << 4)) >> 2);
    // B staging: linear dest (64B rows), full-address inv_swz64 bijection
    const int oB0 = t * 16, oB1 = t * 16 + 8192;
    const int lB0 = inv_swz64(oB0), lB1 = inv_swz64(oB1);
    const ushort* srcB0 = BT + (size_t)(lB0 >> 6) * W_ + ((lB0 & 63) >> 1);
    const ushort* srcB1 = BT + (size_t)(lB1 >> 6) * W_ + ((lB1 & 63) >> 1);

#define STAGE_W(BUF, K0)                                                     \
    {                                                                        \
        char* ab = smem + (BUF) * 16384;                                     \
        char* bb = smem + 32768 + (BUF) * 16384;                             \
        GLOAD16(srcA0 + (K0), ab + oA0);                                     \
        GLOAD16(srcA1 + (K0), ab + oA1);                                     \
        GLOAD16(srcB0 + (K0), bb + oB0);                                     \
        GLOAD16(srcB1 + (K0), bb + oB1);                                     \
    }

    f32x4 acc[4][4];
    #pragma unroll
    for (int m = 0; m < 4; ++m)
        #pragma unroll
        for (int n = 0; n < 4; ++n) acc[m][n] = (f32x4){0.f, 0.f, 0.f, 0.f};

    // prologue: tiles 0 and 1 in flight (8 outstanding/thread)
    STAGE_W(0, 0)
    STAGE_W(1, 32)

    #pragma unroll 1
    for (int kt = 0; kt < 32; ++kt) {
        const int cur = kt & 1;
        // tile kt ready when only the newest 4 loads remain outstanding
        if (kt < 31) asm volatile("s_waitcnt vmcnt(4)" ::: "memory");
        else         asm volatile("s_waitcnt vmcnt(0)" ::: "memory");
        __builtin_amdgcn_sched_barrier(0);
        __builtin_amdgcn_s_barrier();     // all waves: buf[cur] complete

        const char* Af = smem + cur * 16384;
        const char* Bh = smem + 32768 + cur * 16384;
        f16x8 af[4], bf[4];
        #pragma unroll
        for (int m = 0; m < 4; ++m) {
            const int r = wm * 64 + m * 16 + l15;
            const int base = r * 128 + lq * 32;
            const int swz  = (r & 7) << 4;
            const f32x4 a0 = *(const f32x4*)(Af + (base ^ swz));
            const f32x4 a1 = *(const f32x4*)(Af + ((base + 16) ^ swz));
            f16x8 h;
            h[0] = (_Float16)a0[0]; h[1] = (_Float16)a0[1];
            h[2] = (_Float16)a0[2]; h[3] = (_Float16)a0[3];
            h[4] = (_Float16)a1[0]; h[5] = (_Float16)a1[1];
            h[6] = (_Float16)a1[2]; h[7] = (_Float16)a1[3];
            af[m] = h;
        }
        #pragma unroll
        for (int n = 0; n < 4; ++n) {
            const int c = wn * 64 + n * 16 + l15;
            bf[n] = *(const f16x8*)(Bh + ((c * 64 + lq * 16) ^ ((c & 7) << 4)));
        }
        #pragma unroll
        for (int m = 0; m < 4; ++m)
            #pragma unroll
            for (int n = 0; n < 4; ++n)
                acc[m][n] = __builtin_amdgcn_mfma_f32_16x16x32_f16(
                    af[m], bf[n], acc[m][n], 0, 0, 0);

        __builtin_amdgcn_sched_barrier(0);
        __builtin_amdgcn_s_barrier();     // all waves done reading buf[cur]
        if (kt + 2 < 32) STAGE_W(cur, (kt + 2) * 32)
    }
#undef STAGE_W

    // epilogue: w16 -> global
    float bwv[4];
    #pragma unroll
    for (int n = 0; n < 4; ++n) bwv[n] = bw[wn * 64 + n * 16 + l15];
    #pragma unroll
    for (int m = 0; m < 4; ++m)
        #pragma unroll
        for (int reg = 0; reg < 4; ++reg) {
            const size_t r = (size_t)row0 + wm * 64 + m * 16 + lq * 4 + reg;
            #pragma unroll
            for (int n = 0; n < 4; ++n) {
                union { _Float16 h; ushort u; } cv;
                cv.h = (_Float16)(acc[m][n][reg] + bwv[n]);
                Cout[r * WQ_ + wn * 64 + n * 16 + l15] = cv.u;
            }
        }
}

// ---------------------------------------------------------------------------
// Kernel 3: scores — counted-vmcnt pipeline (R18 port; setprio removed).
// L=3 loads/tile -> head wait vmcnt(3). dbuf 48KB + red 2KB.
// BM=128, BN=256(all), BK=32, 8 K-tiles, 512 thr. grid = M/128 = 512
// ---------------------------------------------------------------------------
__global__ __launch_bounds__(512, 2) void gemm_scores_mfma(
    const ushort* __restrict__ A16,   // w M x 256 fp16
    const ushort* __restrict__ BT,    // W1wT fp16 [256][256]
    const float* __restrict__ base_,  // B_ x 256
    const float* __restrict__ W2,     // 256
    const float* __restrict__ b2,     // 1
    float* __restrict__ scores)       // M
{
    __shared__ __align__(16) char smem[49152];
    // A bufs @0,8192: [128][32] f16, 64B rows. B bufs @16384,32768: [256][32] f16
    __shared__ float red[4][128];
    const int t = threadIdx.x;
    const int row0 = blockIdx.x * 128;
    const int b = blockIdx.x >> 5;
    const int lane = t & 63, wave = t >> 6;
    const int wm = wave >> 2, wn = wave & 3;
    const int l15 = lane & 15, lq = lane >> 4;

    // A staging: 1 granule/thread (threads 0..511 cover 8KB)
    const int oA = t * 16;
    const int lA = inv_swz64(oA);
    const ushort* srcA = A16 + (size_t)(row0 + (lA >> 6)) * H_ + ((lA & 63) >> 1);
    // B staging: 2 granules/thread
    const int oB0 = t * 16, oB1 = t * 16 + 8192;
    const int lB0 = inv_swz64(oB0), lB1 = inv_swz64(oB1);
    const ushort* srcB0 = BT + (size_t)(lB0 >> 6) * H_ + ((lB0 & 63) >> 1);
    const ushort* srcB1 = BT + (size_t)(lB1 >> 6) * H_ + ((lB1 & 63) >> 1);

#define STAGE_S(BUF, K0)                                                     \
    {                                                                        \
        char* ab = smem + (BUF) * 8192;                                      \
        char* bb = smem + 16384 + (BUF) * 16384;                             \
        GLOAD16(srcA + (K0), ab + oA);                                       \
        GLOAD16(srcB0 + (K0), bb + oB0);                                     \
        GLOAD16(srcB1 + (K0), bb + oB1);                                     \
    }

    f32x4 acc[4][4];
    #pragma unroll
    for (int m = 0; m < 4; ++m)
        #pragma unroll
        for (int n = 0; n < 4; ++n) acc[m][n] = (f32x4){0.f, 0.f, 0.f, 0.f};

    STAGE_S(0, 0)
    STAGE_S(1, 32)

    #pragma unroll 1
    for (int kt = 0; kt < 8; ++kt) {
        const int cur = kt & 1;
        if (kt < 7) asm volatile("s_waitcnt vmcnt(3)" ::: "memory");
        else        asm volatile("s_waitcnt vmcnt(0)" ::: "memory");
        __builtin_amdgcn_sched_barrier(0);
        __builtin_amdgcn_s_barrier();

        const char* Ah = smem + cur * 8192;
        const char* Bh = smem + 16384 + cur * 16384;
        f16x8 af[4], bf[4];
        #pragma unroll
        for (int m = 0; m < 4; ++m) {
            const int r = wm * 64 + m * 16 + l15;
            af[m] = *(const f16x8*)(Ah + ((r * 64 + lq * 16) ^ ((r & 7) << 4)));
        }
        #pragma unroll
        for (int n = 0; n < 4; ++n) {
            const int c = wn * 64 + n * 16 + l15;
            bf[n] = *(const f16x8*)(Bh + ((c * 64 + lq * 16) ^ ((c & 7) << 4)));
        }
        #pragma unroll
        for (int m = 0; m < 4; ++m)
            #pragma unroll
            for (int n = 0; n < 4; ++n)
                acc[m][n] = __builtin_amdgcn_mfma_f32_16x16x32_f16(
                    af[m], bf[n], acc[m][n], 0, 0, 0);

        __builtin_amdgcn_sched_barrier(0);
        __builtin_amdgcn_s_barrier();
        if (kt + 2 < 8) STAGE_S(cur, (kt + 2) * 32)
    }
#undef STAGE_S

    float basev[4], w2v[4];
    #pragma unroll
    for (int n = 0; n < 4; ++n) {
        const int col = wn * 64 + n * 16 + l15;
        basev[n] = base_[b * H_ + col];
        w2v[n] = W2[col];
    }
    #pragma unroll
    for (int m = 0; m < 4; ++m)
        #pragma unroll
        for (int reg = 0; reg < 4; ++reg) {
            float s = 0.f;
            #pragma unroll
            for (int n = 0; n < 4; ++n) {
                float h = acc[m][n][reg] + basev[n];
                h = fmaxf(h, 0.f);
                s += h * w2v[n];
            }
            s += __shfl_xor(s, 1, 64);
            s += __shfl_xor(s, 2, 64);
            s += __shfl_xor(s, 4, 64);
            s += __shfl_xor(s, 8, 64);
            if (l15 == 0) red[wn][wm * 64 + m * 16 + lq * 4 + reg] = s;
        }
    __syncthreads();
    if (t < 128) {
        scores[row0 + t] = red[0][t] + red[1][t] + red[2][t] + red[3][t] + b2[0];
    }
}

// ---------------------------------------------------------------------------
// Kernel 4: weighted partial sums; m computed locally (identical reduction
// code to finalize -> bitwise-identical m). grid = B_*32, 256 threads.
// ---------------------------------------------------------------------------
__global__ __launch_bounds__(256) void weighted_partial_kernel(
    const ushort* __restrict__ wmat16, const float* __restrict__ scores,
    float* __restrict__ part)
{
    const int blk = blockIdx.x;
    const int b   = blk >> 5;
    const int sl  = blk & 31;
    const int t   = threadIdx.x;
    const int rg  = t >> 5;
    const int q8  = (t & 31) * 8;
    __shared__ float red[8][WQ_];
    __shared__ float mred[4];

    float mv = -1e30f;
    for (int p = t; p < P_; p += 256) mv = fmaxf(mv, scores[b * P_ + p]);
    #pragma unroll
    for (int d = 1; d < 64; d <<= 1) mv = fmaxf(mv, __shfl_xor(mv, d, 64));
    if ((t & 63) == 0) mred[t >> 6] = mv;
    __syncthreads();
    const float m = fmaxf(fmaxf(mred[0], mred[1]), fmaxf(mred[2], mred[3]));

    float acc[8];
    #pragma unroll
    for (int j = 0; j < 8; ++j) acc[j] = 0.f;

    const int p0 = sl * 128 + rg * 16;
    for (int p = p0; p < p0 + 16; ++p) {
        const float e = expf(scores[b * P_ + p] - m);
        const uint4 raw = *(const uint4*)(wmat16 + ((size_t)b * P_ + p) * WQ_ + q8);
        const ushort* u = (const ushort*)&raw;
        #pragma unroll
        for (int j = 0; j < 8; ++j) acc[j] += e * h2f(u[j]);
    }
    #pragma unroll
    for (int j = 0; j < 8; ++j) red[rg][q8 + j] = acc[j];
    __syncthreads();
    float s = 0.f;
    #pragma unroll
    for (int g = 0; g < 8; ++g) s += red[g][t];
    part[(size_t)(b * 32 + sl) * WQ_ + t] = s;
}

// ---------------------------------------------------------------------------
// Kernel 5: finalize — recompute m (same code) and z, out = sum(part)/z.
// ---------------------------------------------------------------------------
__global__ __launch_bounds__(256) void finalize_kernel(
    const float* __restrict__ part, const float* __restrict__ scores,
    float* __restrict__ out)
{
    const int b = blockIdx.x;
    const int t = threadIdx.x;
    __shared__ float mred[4];
    __shared__ float zred[4];

    float mv = -1e30f;
    for (int p = t; p < P_; p += 256) mv = fmaxf(mv, scores[b * P_ + p]);
    #pragma unroll
    for (int d = 1; d < 64; d <<= 1) mv = fmaxf(mv, __shfl_xor(mv, d, 64));
    if ((t & 63) == 0) mred[t >> 6] = mv;
    __syncthreads();
    const float m = fmaxf(fmaxf(mred[0], mred[1]), fmaxf(mred[2], mred[3]));

    float zv = 0.f;
    for (int p = t; p < P_; p += 256) zv += expf(scores[b * P_ + p] - m);
    #pragma unroll
    for (int d = 1; d < 64; d <<= 1) zv += __shfl_xor(zv, d, 64);
    if ((t & 63) == 0) zred[t >> 6] = zv;
    __syncthreads();
    const float z = zred[0] + zred[1] + zred[2] + zred[3];

    float acc = 0.f;
    #pragma unroll
    for (int sl = 0; sl < 32; ++sl) acc += part[(size_t)(b * 32 + sl) * WQ_ + t];
    out[b * WQ_ + t] = acc / z;
}

// ---------------------------------------------------------------------------
extern "C" void kernel_launch(void* const* d_in, const int* in_sizes, int n_in,
                              void* d_out, int out_size, void* d_ws, size_t ws_size,
                              hipStream_t stream) {
    const float* cx = (const float*)d_in[0];
    const float* gx = (const float*)d_in[1];
    const float* wx = (const float*)d_in[2];
    const float* Wc = (const float*)d_in[3];
    const float* bc = (const float*)d_in[4];
    const float* Wg = (const float*)d_in[5];
    const float* bg = (const float*)d_in[6];
    const float* Ww = (const float*)d_in[7];
    const float* bw = (const float*)d_in[8];
    const float* W1 = (const float*)d_in[9];
    const float* b1 = (const float*)d_in[10];
    const float* W2 = (const float*)d_in[11];
    const float* b2 = (const float*)d_in[12];
    float* out = (float*)d_out;

    // workspace layout
    float* ws        = (float*)d_ws;
    ushort* ws_w16   = (ushort*)ws;                      // M_*WQ_ fp16 (32 MB)
    float* ws_scores = ws + (size_t)M_ * WQ_ / 2;        // M_
    float* ws_base   = ws_scores + M_;                   // B_*H_
    float* ws_part   = ws_base + B_ * H_;                // B_*32*WQ_
    ushort* WwT16    = (ushort*)(ws_part + B_ * 32 * WQ_);   // W_*WQ_ fp16
    ushort* W1T16    = WwT16 + (size_t)W_ * WQ_;             // H_*H_ fp16

    setup_kernel<<<96, 256, 0, stream>>>(
        Ww, WwT16, W1 + (size_t)(C_ + G_) * H_, W1T16,
        cx, gx, Wc, bc, Wg, bg, W1, b1, ws_base);

    gemm_w_mfma<<<M_ / 128, 512, 0, stream>>>(wx, WwT16, bw, ws_w16);

    gemm_scores_mfma<<<M_ / 128, 512, 0, stream>>>(
        ws_w16, W1T16, ws_base, W2, b2, ws_scores);

    weighted_partial_kernel<<<B_ * 32, 256, 0, stream>>>(ws_w16, ws_scores, ws_part);

    finalize_kernel<<<B_, 256, 0, stream>>>(ws_part, ws_scores, out);
}